// Round 1
// baseline (5555.276 us; speedup 1.0000x reference)
//
#include <hip/hip_runtime.h>

// RNN_34505767256242: emb lookup -> LSTM(B=16,S=512,E=128,H=256) -> vocab proj (V=32000)
//
// Plan:
//  prep : convert w_ih, w_out f32 -> bf16 in ws
//  gemm<GATHER> : xg[t][b][g] = emb[x[b,t]] @ w_ih^T + b_ih + b_hh   (f32 out, ws)
//  lstm : single WG, 16 waves, w_hh register-resident as MFMA B-frags,
//         h via LDS in A-frag layout, c in f32 regs; writes hs bf16 [t*16+b][256]
//  gemm<PERMUTE> : logits = hs @ w_out^T + b_out, row (t*16+b) -> out row (b*512+t)

typedef __bf16 v8bf __attribute__((ext_vector_type(8)));
typedef __bf16 v4bf __attribute__((ext_vector_type(4)));
typedef float  v4f  __attribute__((ext_vector_type(4)));

#define BATCH 16
#define SEQ   512
#define EMB   128
#define HID   256
#define G4H   1024
#define VOCAB 32000
#define MROWS (BATCH*SEQ)   // 8192

__device__ __forceinline__ float fast_sigmoid(float x) {
    // 1/(1+2^(-x*log2e))
    float e = __builtin_amdgcn_exp2f(-1.442695040888963f * x);
    return __builtin_amdgcn_rcpf(1.0f + e);
}
__device__ __forceinline__ float fast_tanh(float x) {
    // 2*sigmoid(2x)-1
    float e = __builtin_amdgcn_exp2f(-2.885390081777927f * x);
    return 2.0f * __builtin_amdgcn_rcpf(1.0f + e) - 1.0f;
}

// ---------------- f32 -> bf16 convert (vectorized x4) ----------------
__global__ void cvt_kernel(const float* __restrict__ in, __bf16* __restrict__ out, int n4) {
    int i = blockIdx.x * blockDim.x + threadIdx.x;
    if (i < n4) {
        float4 v = ((const float4*)in)[i];
        v4bf p;
        p[0] = (__bf16)v.x; p[1] = (__bf16)v.y; p[2] = (__bf16)v.z; p[3] = (__bf16)v.w;
        ((v4bf*)out)[i] = p;
    }
}

// ---------------- generic 128x128 MFMA GEMM:  C = A * B^T + bias ----------------
// A: [M,K]; GATHER mode: A row m = emb_table[x[m&15, m>>4]] (f32, cvt->bf16)
// B: [N,K] bf16 (w_ih or w_out pre-converted)
// out f32: row map: PERMUTE ? (m&15)*SEQ + (m>>4) : m
template<bool GATHER, bool PERMUTE>
__global__ __launch_bounds__(256)
void gemm_kernel(const __bf16* __restrict__ A, const __bf16* __restrict__ B,
                 const float* __restrict__ bias1, const float* __restrict__ bias2,
                 float* __restrict__ out, int K, int ldout,
                 const int* __restrict__ xidx, const float* __restrict__ emb)
{
    // +8 bf16 row pad -> 80B row stride: <=2-way bank conflicts on frag reads (free)
    __shared__ __bf16 Al[128 * 40];
    __shared__ __bf16 Bl[128 * 40];

    const int tid  = threadIdx.x;
    const int w    = tid >> 6, l = tid & 63;
    const int m    = l & 15, quad = l >> 4;
    const int wm   = w >> 1, wn = w & 1;
    const int row0 = blockIdx.y * 128;
    const int col0 = blockIdx.x * 128;

    v4f acc[4][4];
    #pragma unroll
    for (int i = 0; i < 4; ++i)
        #pragma unroll
        for (int j = 0; j < 4; ++j) {
            v4f z = {0.f, 0.f, 0.f, 0.f};
            acc[i][j] = z;
        }

    for (int k0 = 0; k0 < K; k0 += 32) {
        // ---- stage A tile [128 x 32] ----
        if (GATHER) {
            #pragma unroll
            for (int it = 0; it < 4; ++it) {
                int e = it * 256 + tid;        // 0..1023
                int r = e >> 3, sg = e & 7;    // 8 segs of 4 f32
                int mr = row0 + r;
                int idx = xidx[(mr & 15) * SEQ + (mr >> 4)];
                float4 v = *(const float4*)(emb + (size_t)idx * EMB + k0 + sg * 4);
                v4bf p;
                p[0] = (__bf16)v.x; p[1] = (__bf16)v.y; p[2] = (__bf16)v.z; p[3] = (__bf16)v.w;
                *(v4bf*)&Al[r * 40 + sg * 4] = p;
            }
        } else {
            #pragma unroll
            for (int it = 0; it < 2; ++it) {
                int e = it * 256 + tid;        // 0..511
                int r = e >> 2, sg = e & 3;    // 4 segs of 8 bf16 (16B)
                int4 v = *(const int4*)(A + (size_t)(row0 + r) * K + k0 + sg * 8);
                *(int4*)&Al[r * 40 + sg * 8] = v;
            }
        }
        // ---- stage B tile [128 x 32] ----
        #pragma unroll
        for (int it = 0; it < 2; ++it) {
            int e = it * 256 + tid;
            int r = e >> 2, sg = e & 3;
            int4 v = *(const int4*)(B + (size_t)(col0 + r) * K + k0 + sg * 8);
            *(int4*)&Bl[r * 40 + sg * 8] = v;
        }
        __syncthreads();

        v8bf af[4], bfr[4];
        #pragma unroll
        for (int i = 0; i < 4; ++i)
            af[i] = *(const v8bf*)&Al[(wm * 64 + i * 16 + m) * 40 + quad * 8];
        #pragma unroll
        for (int j = 0; j < 4; ++j)
            bfr[j] = *(const v8bf*)&Bl[(wn * 64 + j * 16 + m) * 40 + quad * 8];

        #pragma unroll
        for (int i = 0; i < 4; ++i)
            #pragma unroll
            for (int j = 0; j < 4; ++j)
                acc[i][j] = __builtin_amdgcn_mfma_f32_16x16x32_bf16(af[i], bfr[j], acc[i][j], 0, 0, 0);
        __syncthreads();
    }

    // ---- epilogue: C row = A-row (quad*4+r), col = B-row (m) ----
    #pragma unroll
    for (int j = 0; j < 4; ++j) {
        int colg = col0 + wn * 64 + j * 16 + m;
        float bs = bias1[colg];
        if (bias2) bs += bias2[colg];
        #pragma unroll
        for (int i = 0; i < 4; ++i) {
            #pragma unroll
            for (int r = 0; r < 4; ++r) {
                int rg = row0 + wm * 64 + i * 16 + quad * 4 + r;
                size_t orow = PERMUTE ? (size_t)((rg & 15) * SEQ + (rg >> 4)) : (size_t)rg;
                out[orow * (size_t)ldout + colg] = acc[i][j][r] + bs;
            }
        }
    }
}

// ---------------- LSTM recurrence: single WG, 16 waves, weights in registers ----------------
// xg: [SEQ][BATCH][4H] f32 (precomputed input gates incl. both biases)
// w_hh: [4H][H] f32 (gate order i,f,g,o)
// hs out: bf16 [SEQ*BATCH][H], row = t*16 + b
__global__ __launch_bounds__(1024)
void lstm_kernel(const float* __restrict__ xg, const float* __restrict__ w_hh,
                 __bf16* __restrict__ hs)
{
    // h in A-frag layout: elem (k>>3)*128 + b*8 + (k&7); frag s read at elems [s*512 + l*8]
    __shared__ __bf16 h_lds[4096];

    const int tid  = threadIdx.x;
    const int w    = tid >> 6;      // wave 0..15 -> owns hids [16w, 16w+16)
    const int l    = tid & 63;
    const int m    = l & 15;        // within-tile col (hid offset / gate row)
    const int quad = l >> 4;

    // ---- load w_hh as B-frags: bw[q][s] = W[q*256 + 16w + m][32s + quad*8 + j] ----
    v8bf bw[4][8];
    #pragma unroll
    for (int q = 0; q < 4; ++q)
        #pragma unroll
        for (int s = 0; s < 8; ++s) {
            const float* src = w_hh + (size_t)(q * 256 + w * 16 + m) * HID + s * 32 + quad * 8;
            float4 v0 = *(const float4*)(src);
            float4 v1 = *(const float4*)(src + 4);
            v8bf f;
            f[0] = (__bf16)v0.x; f[1] = (__bf16)v0.y; f[2] = (__bf16)v0.z; f[3] = (__bf16)v0.w;
            f[4] = (__bf16)v1.x; f[5] = (__bf16)v1.y; f[6] = (__bf16)v1.z; f[7] = (__bf16)v1.w;
            bw[q][s] = f;
        }

    for (int i = tid; i < 4096; i += 1024) h_lds[i] = (__bf16)0.0f;

    float c0[4] = {0.f, 0.f, 0.f, 0.f};   // c[b = quad*4+r][hid = 16w+m]

    // prefetch xg for t=0
    float xgc[16];
    #pragma unroll
    for (int q = 0; q < 4; ++q)
        #pragma unroll
        for (int r = 0; r < 4; ++r)
            xgc[q * 4 + r] = xg[(size_t)(quad * 4 + r) * G4H + q * 256 + w * 16 + m];

    __syncthreads();

    for (int t = 0; t < SEQ; ++t) {
        // read A-frags (previous h), conflict-free linear ds_read_b128
        v8bf af[8];
        #pragma unroll
        for (int s = 0; s < 8; ++s)
            af[s] = *(const v8bf*)&h_lds[s * 512 + l * 8];
        __syncthreads();   // everyone has read old h before it is overwritten

        // prefetch next step's xg (independent of h; overlaps with MFMA chain)
        float xgn[16];
        {
            int tn = (t < SEQ - 1) ? t + 1 : t;
            const float* xgt = xg + (size_t)tn * BATCH * G4H;
            #pragma unroll
            for (int q = 0; q < 4; ++q)
                #pragma unroll
                for (int r = 0; r < 4; ++r)
                    xgn[q * 4 + r] = xgt[(size_t)(quad * 4 + r) * G4H + q * 256 + w * 16 + m];
        }

        // gates = xg + h @ W^T, f32 accum (xg as C-init)
        v4f accq[4];
        #pragma unroll
        for (int q = 0; q < 4; ++q) {
            v4f acc;
            #pragma unroll
            for (int r = 0; r < 4; ++r) acc[r] = xgc[q * 4 + r];
            #pragma unroll
            for (int s = 0; s < 8; ++s)
                acc = __builtin_amdgcn_mfma_f32_16x16x32_bf16(af[s], bw[q][s], acc, 0, 0, 0);
            accq[q] = acc;
        }

        // nonlinearities + state update; write new h to LDS (A-frag layout) + global hs
        #pragma unroll
        for (int r = 0; r < 4; ++r) {
            float i_ = fast_sigmoid(accq[0][r]);
            float f_ = fast_sigmoid(accq[1][r]);
            float g_ = fast_tanh(accq[2][r]);
            float o_ = fast_sigmoid(accq[3][r]);
            float c  = f_ * c0[r] + i_ * g_;
            c0[r] = c;
            float h = o_ * fast_tanh(c);

            int b = quad * 4 + r;
            int k = w * 16 + m;
            __bf16 hb = (__bf16)h;
            h_lds[(k >> 3) * 128 + b * 8 + (k & 7)] = hb;
            hs[(size_t)(t * 16 + b) * HID + k] = hb;
        }
        __syncthreads();   // new h visible to all waves

        #pragma unroll
        for (int i = 0; i < 16; ++i) xgc[i] = xgn[i];
    }
}

extern "C" void kernel_launch(void* const* d_in, const int* in_sizes, int n_in,
                              void* d_out, int out_size, void* d_ws, size_t ws_size,
                              hipStream_t stream) {
    const int*   x     = (const int*)d_in[0];      // [B,S] int32
    const float* emb   = (const float*)d_in[1];    // [VOCAB, EMB]
    const float* w_ih  = (const float*)d_in[2];    // [4H, EMB]
    const float* w_hh  = (const float*)d_in[3];    // [4H, H]
    const float* b_ih  = (const float*)d_in[4];    // [4H]
    const float* b_hh  = (const float*)d_in[5];    // [4H]
    const float* w_out = (const float*)d_in[6];    // [VOCAB, H]
    const float* b_out = (const float*)d_in[7];    // [VOCAB]
    float* out = (float*)d_out;

    char* ws = (char*)d_ws;
    float*  xgbuf = (float*)(ws);                         // 8192*1024*4 = 33,554,432 B
    __bf16* hsbuf = (__bf16*)(ws + 33554432);             // 8192*256*2  =  4,194,304 B
    __bf16* wihb  = (__bf16*)(ws + 37748736);             // 1024*128*2  =    262,144 B
    __bf16* woutb = (__bf16*)(ws + 38010880);             // 32000*256*2 = 16,384,000 B

    // prep: weight conversions to bf16
    cvt_kernel<<<(G4H * EMB / 4 + 255) / 256, 256, 0, stream>>>(w_ih, wihb, G4H * EMB / 4);
    cvt_kernel<<<(VOCAB * HID / 4 + 255) / 256, 256, 0, stream>>>(w_out, woutb, VOCAB * HID / 4);

    // phase 1: xg = emb[x] @ w_ih^T + b_ih + b_hh   -> [S][B][4H] f32
    gemm_kernel<true, false><<<dim3(G4H / 128, MROWS / 128), 256, 0, stream>>>(
        nullptr, wihb, b_ih, b_hh, xgbuf, EMB, G4H, x, emb);

    // phase 2: sequential LSTM (single WG)
    lstm_kernel<<<1, 1024, 0, stream>>>(xgbuf, w_hh, hsbuf);

    // phase 3: logits = hs @ w_out^T + b_out  -> out[b][t][v]
    gemm_kernel<false, true><<<dim3(VOCAB / 128, MROWS / 128), 256, 0, stream>>>(
        hsbuf, woutb, b_out, nullptr, out, HID, VOCAB, nullptr, nullptr);
}